// Round 1
// baseline (468.809 us; speedup 1.0000x reference)
//
#include <hip/hip_runtime.h>
#include <math.h>

#define N 64
#define S 64
#define C 128
#define P 32
#define KCLS 1000
#define HPG 24
#define C3 384
#define NS 4096   /* N*S */
#define EPSV 1e-5f

// ---- workspace layout (float offsets) ----
#define WS_XT   0                              // [P][C3][NS]      50331648
#define WS_H    (WS_XT + P*C3*NS)              // [P][HPG][NS]      3145728
#define WS_W1T  (WS_H + P*HPG*NS)              // [P][C3][HPG]       294912
#define WS_BNP  (WS_W1T + P*C3*HPG)            // [P*HPG][16][2]      24576
#define WS_BNSS (WS_BNP + P*HPG*16*2)          // [P*HPG][2]           1536
#define WS_Y    (WS_BNSS + P*HPG*2)            // [P][N][C3]         786432
#define WS_Z    (WS_Y + P*N*C3)                // [P][N]               2048
#define WS_PF   (WS_Z + P*N)                   // [P][C][N]          262144

// ============ K0: transpose t_{f,s,l}[n,s,c,p] -> xT[p][i][n*S+s] ============
__global__ __launch_bounds__(256) void k0_transpose(
    const float* __restrict__ tf, const float* __restrict__ ts,
    const float* __restrict__ tl, float* __restrict__ xT)
{
  int cchunk = blockIdx.x;      // 0..31 (4 c each)
  int n = blockIdx.y;           // 0..63
  int z = blockIdx.z;           // 0..2
  const float* src = (z == 0) ? tf : (z == 1) ? ts : tl;
  int c0 = cchunk * 4;
  __shared__ float xls[4][64][33];
  int t = threadIdx.x;
  const float* base = src + (size_t)n * S * C * P;
  #pragma unroll
  for (int j = 0; j < 32; ++j) {
    int e = t + 256 * j;
    int p  = e & 31;
    int cc = (e >> 5) & 3;
    int s  = e >> 7;
    xls[cc][s][p] = base[s * C * P + (c0 + cc) * P + p];
  }
  __syncthreads();
  #pragma unroll
  for (int j = 0; j < 32; ++j) {
    int e = t + 256 * j;
    int s  = e & 63;
    int cc = (e >> 6) & 3;
    int p  = e >> 8;
    int i = z * C + c0 + cc;
    xT[(size_t)(p * C3 + i) * NS + n * S + s] = xls[cc][s][p];
  }
}

// ============ K0b: w1[p][o][i] -> w1T[p][i][o] ============
__global__ __launch_bounds__(256) void k0b_w1t(
    const float* __restrict__ w1, float* __restrict__ w1T)
{
  int p = blockIdx.x;
  int t = threadIdx.x;
  for (int e = t; e < HPG * C3; e += 256) {
    int o = e / C3, i = e % C3;
    w1T[p * HPG * C3 + i * HPG + o] = w1[p * HPG * C3 + e];
  }
}

// ============ K1: h[p][o][ns] = sum_i w1T[p][i][o] * xT[p][i][ns]; BN partials ============
__global__ __launch_bounds__(256) void k1_h(
    const float* __restrict__ xT, const float* __restrict__ w1T,
    float* __restrict__ h, float* __restrict__ bnpart)
{
  int nst = blockIdx.x;  // 0..15
  int p   = blockIdx.y;  // 0..31
  int t = threadIdx.x;
  int ns = nst * 256 + t;
  const float* xcol = xT + (size_t)p * C3 * NS + ns;
  const float* w1p  = w1T + p * C3 * HPG;
  float acc[HPG];
  #pragma unroll
  for (int o = 0; o < HPG; ++o) acc[o] = 0.f;
  #pragma unroll 4
  for (int i = 0; i < C3; ++i) {
    float xv = xcol[(size_t)i * NS];
    const float* wrow = w1p + i * HPG;   // wave-uniform -> scalar loads
    #pragma unroll
    for (int o = 0; o < HPG; ++o) acc[o] += xv * wrow[o];
  }
  float* hp = h + (size_t)p * HPG * NS + ns;
  #pragma unroll
  for (int o = 0; o < HPG; ++o) hp[o * NS] = acc[o];
  // BN partial sums (sum, sumsq) over this block's 256 ns
  __shared__ float wred[4][HPG][2];
  int w = t >> 6, l = t & 63;
  #pragma unroll
  for (int o = 0; o < HPG; ++o) {
    float s = acc[o], q = acc[o] * acc[o];
    #pragma unroll
    for (int m = 1; m < 64; m <<= 1) {
      s += __shfl_xor(s, m, 64);
      q += __shfl_xor(q, m, 64);
    }
    if (l == 0) { wred[w][o][0] = s; wred[w][o][1] = q; }
  }
  __syncthreads();
  if (t < HPG) {
    float s = wred[0][t][0] + wred[1][t][0] + wred[2][t][0] + wred[3][t][0];
    float q = wred[0][t][1] + wred[1][t][1] + wred[2][t][1] + wred[3][t][1];
    bnpart[((p * HPG + t) * 16 + nst) * 2 + 0] = s;
    bnpart[((p * HPG + t) * 16 + nst) * 2 + 1] = q;
  }
}

// ============ K2: finalize BN1 scale/shift ============
__global__ void k2_bnstat(const float* __restrict__ bnpart,
    const float* __restrict__ g, const float* __restrict__ b,
    float* __restrict__ bnss)
{
  int t = threadIdx.x;  // 768 threads = P*HPG
  if (t >= P * HPG) return;
  float sum = 0.f, sq = 0.f;
  #pragma unroll
  for (int j = 0; j < 16; ++j) {
    sum += bnpart[t * 32 + j * 2];
    sq  += bnpart[t * 32 + j * 2 + 1];
  }
  float mu  = sum / (float)NS;
  float var = sq / (float)NS - mu * mu;
  float sc = g[t] * rsqrtf(var + EPSV);
  bnss[t * 2]     = sc;
  bnss[t * 2 + 1] = b[t] - mu * sc;
}

// ============ K3: score, Z, argmax, y[n,p,i], selected gather ============
__global__ __launch_bounds__(256) void k3_score_y(
    const float* __restrict__ xT, const float* __restrict__ h,
    const float* __restrict__ bnss, const float* __restrict__ w2,
    const float* __restrict__ tf, float* __restrict__ y,
    float* __restrict__ z, float* __restrict__ out_spf)
{
  int n = blockIdx.x, p = blockIdx.y;
  int t = threadIdx.x, w = t >> 6, l = t & 63;
  __shared__ float ylds[C3];
  __shared__ int midx_s;
  // score for frame s = l (each wave computes redundantly)
  float ssum = 0.f;
  const float* hp = h + (size_t)p * HPG * NS + n * S;
  #pragma unroll
  for (int o = 0; o < HPG; ++o) {
    float hv = hp[(size_t)o * NS + l];
    float sc = bnss[(p * HPG + o) * 2];
    float sh = bnss[(p * HPG + o) * 2 + 1];
    float v = hv * sc + sh;
    v = (v >= 0.f) ? v : 0.01f * v;
    ssum += w2[p * HPG + o] * v;
  }
  float scr = 1.f / (1.f + expf(-ssum));
  // Z (sum over s) and argmax (first max)
  float zs = scr;
  #pragma unroll
  for (int m = 1; m < 64; m <<= 1) zs += __shfl_xor(zs, m, 64);
  float mv = scr; int mi = l;
  #pragma unroll
  for (int m = 1; m < 64; m <<= 1) {
    float ov = __shfl_xor(mv, m, 64);
    int   oi = __shfl_xor(mi, m, 64);
    if (ov > mv || (ov == mv && oi < mi)) { mv = ov; mi = oi; }
  }
  if (t == 0) { z[p * N + n] = zs; midx_s = mi; }
  // y[i] = sum_s xT[p][i][n,s] * score[s]
  const float* xp = xT + (size_t)p * C3 * NS + n * S;
  for (int ii = w; ii < C3; ii += 4) {
    float v = xp[(size_t)ii * NS + l] * scr;
    #pragma unroll
    for (int m = 1; m < 64; m <<= 1) v += __shfl_xor(v, m, 64);
    if (l == 0) ylds[ii] = v;
  }
  __syncthreads();
  float* yp = y + (p * N + n) * C3;
  for (int j = t; j < C3; j += 256) yp[j] = ylds[j];
  // selected_part_feature[p][n][c] = t_f[n, midx, c, p]
  int mi2 = midx_s;
  if (t < C) {
    float v = tf[(size_t)n * S * C * P + (size_t)mi2 * C * P + t * P + p];
    out_spf[(p * N + n) * C + t] = v;
  }
}

// ============ K4: wpv = (wd . y)/Z, BN over n, write wpv out + pf[p][c][n] ============
__global__ __launch_bounds__(256) void k4_wpv(
    const float* __restrict__ y, const float* __restrict__ z,
    const float* __restrict__ wd, const float* __restrict__ g,
    const float* __restrict__ b, float* __restrict__ out_wpv,
    float* __restrict__ pf)
{
  int p = blockIdx.x;
  int t = threadIdx.x, w = t >> 6, l = t & 63;   // l = n
  __shared__ float ych[N][100];       // 96 i + pad4
  __shared__ float wpv_lds[N][132];
  __shared__ float zinv[N];
  __shared__ float s2[C], sh2[C];
  if (t < N) zinv[t] = 1.f / z[p * N + t];
  float acc[16][2];
  #pragma unroll
  for (int it = 0; it < 16; ++it) { acc[it][0] = 0.f; acc[it][1] = 0.f; }
  const float* yp  = y  + p * N * C3;
  const float* wdp = wd + p * C * C3;
  for (int ch = 0; ch < 4; ++ch) {
    __syncthreads();
    for (int j = 0; j < 24; ++j) {
      int e = t + 256 * j;
      int i = e % 96, nn = e / 96;
      ych[nn][i] = yp[nn * C3 + ch * 96 + i];
    }
    __syncthreads();
    #pragma unroll
    for (int it = 0; it < 16; ++it) {
      int cp = it * 4 + w;
      int c0 = cp * 2, c1 = c0 + 1;
      const float* w0 = wdp + c0 * C3 + ch * 96;  // wave-uniform
      const float* w1r = wdp + c1 * C3 + ch * 96;
      float a0 = acc[it][0], a1 = acc[it][1];
      #pragma unroll 4
      for (int i4 = 0; i4 < 24; ++i4) {
        float4 y4 = *(const float4*)&ych[l][i4 * 4];
        float4 wa = *(const float4*)&w0[i4 * 4];
        float4 wb = *(const float4*)&w1r[i4 * 4];
        a0 += y4.x * wa.x + y4.y * wa.y + y4.z * wa.z + y4.w * wa.w;
        a1 += y4.x * wb.x + y4.y * wb.y + y4.z * wb.z + y4.w * wb.w;
      }
      acc[it][0] = a0; acc[it][1] = a1;
    }
  }
  __syncthreads();
  #pragma unroll
  for (int it = 0; it < 16; ++it) {
    int cp = it * 4 + w;
    wpv_lds[l][cp * 2]     = acc[it][0] * zinv[l];
    wpv_lds[l][cp * 2 + 1] = acc[it][1] * zinv[l];
  }
  __syncthreads();
  if (t < C) {
    float sum = 0.f, sq = 0.f;
    #pragma unroll 8
    for (int nn = 0; nn < N; ++nn) {
      float v = wpv_lds[nn][t];
      sum += v; sq += v * v;
    }
    float mu = sum / (float)N, var = sq / (float)N - mu * mu;
    float sc = g[p * C + t] * rsqrtf(var + EPSV);
    s2[t] = sc; sh2[t] = b[p * C + t] - mu * sc;
  }
  __syncthreads();
  // pass A: weighted_part_vector out (p,n,c) coalesced over c
  for (int j = 0; j < 32; ++j) {
    int e = t + 256 * j; int c = e & 127, nn = e >> 7;
    out_wpv[(p * N + nn) * C + c] = wpv_lds[nn][c];
  }
  // pass B: pf[p][c][n] coalesced over n
  for (int j = 0; j < 32; ++j) {
    int e = t + 256 * j; int nn = e & 63, c = e >> 6;
    pf[(p * C + c) * N + nn] = wpv_lds[nn][c] * s2[c] + sh2[c];
  }
}

// ============ K5: part_classification[p][n][k] = sum_c pf[p][c][n]*fc[c][k] ============
__global__ __launch_bounds__(256) void k5_fc(
    const float* __restrict__ pf, const float* __restrict__ fc,
    float* __restrict__ out0)
{
  int kt = blockIdx.x;   // 0..3
  int p  = blockIdx.y;
  int t = threadIdx.x;
  int k = kt * 256 + t;
  bool ok = k < KCLS;
  int kk = ok ? k : (KCLS - 1);
  float acc[N];
  #pragma unroll
  for (int nn = 0; nn < N; ++nn) acc[nn] = 0.f;
  const float* pfp = pf + p * C * N;
  for (int c = 0; c < C; ++c) {
    float fv = fc[c * KCLS + kk];
    const float* row = pfp + c * N;  // wave-uniform -> scalar loads
    #pragma unroll
    for (int nn = 0; nn < N; ++nn) acc[nn] += row[nn] * fv;
  }
  if (ok) {
    #pragma unroll 4
    for (int nn = 0; nn < N; ++nn)
      out0[(size_t)(p * N + nn) * KCLS + k] = acc[nn];
  }
}

extern "C" void kernel_launch(void* const* d_in, const int* in_sizes, int n_in,
                              void* d_out, int out_size, void* d_ws, size_t ws_size,
                              hipStream_t stream)
{
  const float* tf = (const float*)d_in[0];
  const float* ts = (const float*)d_in[1];
  const float* tl = (const float*)d_in[2];
  const float* w1 = (const float*)d_in[3];
  const float* g1 = (const float*)d_in[4];
  const float* b1 = (const float*)d_in[5];
  const float* w2 = (const float*)d_in[6];
  const float* wd = (const float*)d_in[7];
  const float* g  = (const float*)d_in[8];
  const float* b  = (const float*)d_in[9];
  const float* fc = (const float*)d_in[10];

  float* ws   = (float*)d_ws;
  float* xT   = ws + WS_XT;
  float* h    = ws + WS_H;
  float* w1T  = ws + WS_W1T;
  float* bnp  = ws + WS_BNP;
  float* bnss = ws + WS_BNSS;
  float* y    = ws + WS_Y;
  float* z    = ws + WS_Z;
  float* pf   = ws + WS_PF;

  float* out0 = (float*)d_out;         // part_classification (P,N,K)
  float* out1 = out0 + P * N * KCLS;   // weighted_part_vector (P,N,C)
  float* out2 = out1 + P * N * C;      // selected_part_feature (P,N,C)

  k0_transpose<<<dim3(32, 64, 3), 256, 0, stream>>>(tf, ts, tl, xT);
  k0b_w1t<<<32, 256, 0, stream>>>(w1, w1T);
  k1_h<<<dim3(16, 32), 256, 0, stream>>>(xT, w1T, h, bnp);
  k2_bnstat<<<1, 768, 0, stream>>>(bnp, g1, b1, bnss);
  k3_score_y<<<dim3(64, 32), 256, 0, stream>>>(xT, h, bnss, w2, tf, y, z, out2);
  k4_wpv<<<32, 256, 0, stream>>>(y, z, wd, g, b, out1, pf);
  k5_fc<<<dim3(4, 32), 256, 0, stream>>>(pf, fc, out0);
}

// Round 2
// 330.269 us; speedup vs baseline: 1.4195x; 1.4195x over previous
//
#include <hip/hip_runtime.h>
#include <math.h>

#define N 64
#define S 64
#define C 128
#define P 32
#define KCLS 1000
#define HPG 24
#define C3 384
#define NS 4096   /* N*S */
#define EPSV 1e-5f

// ---- workspace layout (float offsets) ----
#define WS_XT   0                              // [P][C3][NS]      50331648
#define WS_H    (WS_XT + P*C3*NS)              // [P][HPG][NS]      3145728
#define WS_W1T  (WS_H + P*HPG*NS)              // [P][C3][HPG]       294912
#define WS_BNP  (WS_W1T + P*C3*HPG)            // [P*HPG][16][2]      24576
#define WS_BNSS (WS_BNP + P*HPG*16*2)          // [P*HPG][2]           1536
#define WS_Y    (WS_BNSS + P*HPG*2)            // [P][N][C3]         786432
#define WS_Z    (WS_Y + P*N*C3)                // [P][N]               2048
#define WS_PF   (WS_Z + P*N)                   // [P][C][N]          262144

// ============ K0: transpose t_{f,s,l}[n,s,c,p] -> xT[p][i][n*S+s] ============
__global__ __launch_bounds__(256) void k0_transpose(
    const float* __restrict__ tf, const float* __restrict__ ts,
    const float* __restrict__ tl, float* __restrict__ xT)
{
  int cchunk = blockIdx.x;      // 0..31 (4 c each)
  int n = blockIdx.y;           // 0..63
  int z = blockIdx.z;           // 0..2
  const float* src = (z == 0) ? tf : (z == 1) ? ts : tl;
  int c0 = cchunk * 4;
  __shared__ float xls[4][64][33];
  int t = threadIdx.x;
  const float* base = src + (size_t)n * S * C * P;
  #pragma unroll
  for (int j = 0; j < 32; ++j) {
    int e = t + 256 * j;
    int p  = e & 31;
    int cc = (e >> 5) & 3;
    int s  = e >> 7;
    xls[cc][s][p] = base[s * C * P + (c0 + cc) * P + p];
  }
  __syncthreads();
  #pragma unroll
  for (int j = 0; j < 32; ++j) {
    int e = t + 256 * j;
    int s  = e & 63;
    int cc = (e >> 6) & 3;
    int p  = e >> 8;
    int i = z * C + c0 + cc;
    xT[(size_t)(p * C3 + i) * NS + n * S + s] = xls[cc][s][p];
  }
}

// ============ K0b: w1[p][o][i] -> w1T[p][i][o] ============
__global__ __launch_bounds__(256) void k0b_w1t(
    const float* __restrict__ w1, float* __restrict__ w1T)
{
  int p = blockIdx.x;
  int t = threadIdx.x;
  for (int e = t; e < HPG * C3; e += 256) {
    int o = e / C3, i = e % C3;
    w1T[p * HPG * C3 + i * HPG + o] = w1[p * HPG * C3 + e];
  }
}

// ============ K1: h[p][o][ns] = sum_i w1T[p][i][o] * xT[p][i][ns]; BN partials ============
__global__ __launch_bounds__(256) void k1_h(
    const float* __restrict__ xT, const float* __restrict__ w1T,
    float* __restrict__ h, float* __restrict__ bnpart)
{
  int nst = blockIdx.x;  // 0..15
  int p   = blockIdx.y;  // 0..31
  int t = threadIdx.x;
  int ns = nst * 256 + t;
  const float* xcol = xT + (size_t)p * C3 * NS + ns;
  const float* w1p  = w1T + p * C3 * HPG;
  float acc[HPG];
  #pragma unroll
  for (int o = 0; o < HPG; ++o) acc[o] = 0.f;
  #pragma unroll 4
  for (int i = 0; i < C3; ++i) {
    float xv = xcol[(size_t)i * NS];
    const float* wrow = w1p + i * HPG;   // wave-uniform -> scalar loads
    #pragma unroll
    for (int o = 0; o < HPG; ++o) acc[o] += xv * wrow[o];
  }
  float* hp = h + (size_t)p * HPG * NS + ns;
  #pragma unroll
  for (int o = 0; o < HPG; ++o) hp[o * NS] = acc[o];
  // BN partial sums (sum, sumsq) over this block's 256 ns
  __shared__ float wred[4][HPG][2];
  int w = t >> 6, l = t & 63;
  #pragma unroll
  for (int o = 0; o < HPG; ++o) {
    float s = acc[o], q = acc[o] * acc[o];
    #pragma unroll
    for (int m = 1; m < 64; m <<= 1) {
      s += __shfl_xor(s, m, 64);
      q += __shfl_xor(q, m, 64);
    }
    if (l == 0) { wred[w][o][0] = s; wred[w][o][1] = q; }
  }
  __syncthreads();
  if (t < HPG) {
    float s = wred[0][t][0] + wred[1][t][0] + wred[2][t][0] + wred[3][t][0];
    float q = wred[0][t][1] + wred[1][t][1] + wred[2][t][1] + wred[3][t][1];
    bnpart[((p * HPG + t) * 16 + nst) * 2 + 0] = s;
    bnpart[((p * HPG + t) * 16 + nst) * 2 + 1] = q;
  }
}

// ============ K2: finalize BN1 scale/shift ============
__global__ void k2_bnstat(const float* __restrict__ bnpart,
    const float* __restrict__ g, const float* __restrict__ b,
    float* __restrict__ bnss)
{
  int t = threadIdx.x;  // 768 threads = P*HPG
  if (t >= P * HPG) return;
  float sum = 0.f, sq = 0.f;
  #pragma unroll
  for (int j = 0; j < 16; ++j) {
    sum += bnpart[t * 32 + j * 2];
    sq  += bnpart[t * 32 + j * 2 + 1];
  }
  float mu  = sum / (float)NS;
  float var = sq / (float)NS - mu * mu;
  float sc = g[t] * rsqrtf(var + EPSV);
  bnss[t * 2]     = sc;
  bnss[t * 2 + 1] = b[t] - mu * sc;
}

// ============ K3: score, Z, argmax, y[n,p,i], selected gather ============
__global__ __launch_bounds__(256) void k3_score_y(
    const float* __restrict__ xT, const float* __restrict__ h,
    const float* __restrict__ bnss, const float* __restrict__ w2,
    const float* __restrict__ tf, float* __restrict__ y,
    float* __restrict__ z, float* __restrict__ out_spf)
{
  int n = blockIdx.x, p = blockIdx.y;
  int t = threadIdx.x, w = t >> 6, l = t & 63;
  __shared__ float ylds[C3];
  __shared__ int midx_s;
  // score for frame s = l (each wave computes redundantly)
  float ssum = 0.f;
  const float* hp = h + (size_t)p * HPG * NS + n * S;
  #pragma unroll
  for (int o = 0; o < HPG; ++o) {
    float hv = hp[(size_t)o * NS + l];
    float sc = bnss[(p * HPG + o) * 2];
    float sh = bnss[(p * HPG + o) * 2 + 1];
    float v = hv * sc + sh;
    v = (v >= 0.f) ? v : 0.01f * v;
    ssum += w2[p * HPG + o] * v;
  }
  float scr = 1.f / (1.f + expf(-ssum));
  // Z (sum over s) and argmax (first max)
  float zs = scr;
  #pragma unroll
  for (int m = 1; m < 64; m <<= 1) zs += __shfl_xor(zs, m, 64);
  float mv = scr; int mi = l;
  #pragma unroll
  for (int m = 1; m < 64; m <<= 1) {
    float ov = __shfl_xor(mv, m, 64);
    int   oi = __shfl_xor(mi, m, 64);
    if (ov > mv || (ov == mv && oi < mi)) { mv = ov; mi = oi; }
  }
  if (t == 0) { z[p * N + n] = zs; midx_s = mi; }
  // y[i] = sum_s xT[p][i][n,s] * score[s]
  const float* xp = xT + (size_t)p * C3 * NS + n * S;
  for (int ii = w; ii < C3; ii += 4) {
    float v = xp[(size_t)ii * NS + l] * scr;
    #pragma unroll
    for (int m = 1; m < 64; m <<= 1) v += __shfl_xor(v, m, 64);
    if (l == 0) ylds[ii] = v;
  }
  __syncthreads();
  float* yp = y + (p * N + n) * C3;
  for (int j = t; j < C3; j += 256) yp[j] = ylds[j];
  // selected_part_feature[p][n][c] = t_f[n, midx, c, p]
  int mi2 = midx_s;
  if (t < C) {
    float v = tf[(size_t)n * S * C * P + (size_t)mi2 * C * P + t * P + p];
    out_spf[(p * N + n) * C + t] = v;
  }
}

// ============ K4: wpv = (wd . y)/Z, BN over n, write wpv + pf[p][c][n] ============
// grid (P, 8): block = 16 c x all 64 n.  thread: n = t&63, cg = t>>6 (4 c each)
__global__ __launch_bounds__(256) void k4_wpv(
    const float* __restrict__ y, const float* __restrict__ z,
    const float* __restrict__ wd, const float* __restrict__ g,
    const float* __restrict__ b, float* __restrict__ out_wpv,
    float* __restrict__ pf)
{
  int p   = blockIdx.x;
  int cch = blockIdx.y;             // 0..7
  int t = threadIdx.x;
  int n = t & 63, cg = t >> 6;
  int cbase = cch * 16 + cg * 4;
  __shared__ float ych[96][66];     // i-major, stride 66 -> 2-way (free)
  float acc[4] = {0.f, 0.f, 0.f, 0.f};
  const float* yp  = y  + (size_t)p * N * C3;
  const float* wdp = wd + (size_t)p * C * C3;
  for (int ch = 0; ch < 4; ++ch) {
    __syncthreads();
    #pragma unroll
    for (int j = 0; j < 24; ++j) {
      int e = t + 256 * j;
      int i = e % 96, nn = e / 96;
      ych[i][nn] = yp[nn * C3 + ch * 96 + i];
    }
    __syncthreads();
    #pragma unroll
    for (int sub = 0; sub < 4; ++sub) {
      float yr[24];
      #pragma unroll
      for (int kk = 0; kk < 24; ++kk) yr[kk] = ych[sub * 24 + kk][n];
      int ibase = ch * 96 + sub * 24;
      #pragma unroll
      for (int cl = 0; cl < 4; ++cl) {
        const float4* w4 = (const float4*)(wdp + (size_t)(cbase + cl) * C3 + ibase);
        float a = 0.f;
        #pragma unroll
        for (int q = 0; q < 6; ++q) {
          float4 wv = w4[q];
          a += yr[q*4+0] * wv.x + yr[q*4+1] * wv.y
             + yr[q*4+2] * wv.z + yr[q*4+3] * wv.w;
        }
        acc[cl] += a;
      }
    }
  }
  float zinv = 1.f / z[p * N + n];
  #pragma unroll
  for (int cl = 0; cl < 4; ++cl) acc[cl] *= zinv;
  // BN over n (wave lanes are exactly n=0..63 for fixed cg)
  #pragma unroll
  for (int cl = 0; cl < 4; ++cl) {
    float v = acc[cl];
    float s = v, q = v * v;
    #pragma unroll
    for (int m = 1; m < 64; m <<= 1) {
      s += __shfl_xor(s, m, 64);
      q += __shfl_xor(q, m, 64);
    }
    float mu  = s * (1.f / 64.f);
    float var = q * (1.f / 64.f) - mu * mu;
    int c = cbase + cl;
    float sc = g[p * C + c] * rsqrtf(var + EPSV);
    float sh = b[p * C + c] - mu * sc;
    pf[((size_t)p * C + c) * N + n] = v * sc + sh;   // coalesced over n
  }
  float4 wout = make_float4(acc[0], acc[1], acc[2], acc[3]);
  *(float4*)(out_wpv + ((size_t)p * N + n) * C + cbase) = wout;
}

// ============ K5: part_classification[p][n][k] = sum_c pf[p][c][n]*fc[c][k] ============
__global__ __launch_bounds__(256) void k5_fc(
    const float* __restrict__ pf, const float* __restrict__ fc,
    float* __restrict__ out0)
{
  int kt = blockIdx.x;   // 0..3
  int p  = blockIdx.y;
  int t = threadIdx.x;
  int k = kt * 256 + t;
  bool ok = k < KCLS;
  int kk = ok ? k : (KCLS - 1);
  float acc[N];
  #pragma unroll
  for (int nn = 0; nn < N; ++nn) acc[nn] = 0.f;
  const float4* pf4 = (const float4*)(pf + (size_t)p * C * N);
  for (int c = 0; c < C; ++c) {
    float fv = fc[c * KCLS + kk];
    #pragma unroll
    for (int j = 0; j < 16; ++j) {
      float4 r = pf4[c * 16 + j];   // wave-uniform -> L1 broadcast
      acc[j*4+0] += r.x * fv; acc[j*4+1] += r.y * fv;
      acc[j*4+2] += r.z * fv; acc[j*4+3] += r.w * fv;
    }
  }
  if (ok) {
    #pragma unroll 4
    for (int nn = 0; nn < N; ++nn)
      out0[(size_t)(p * N + nn) * KCLS + k] = acc[nn];
  }
}

extern "C" void kernel_launch(void* const* d_in, const int* in_sizes, int n_in,
                              void* d_out, int out_size, void* d_ws, size_t ws_size,
                              hipStream_t stream)
{
  const float* tf = (const float*)d_in[0];
  const float* ts = (const float*)d_in[1];
  const float* tl = (const float*)d_in[2];
  const float* w1 = (const float*)d_in[3];
  const float* g1 = (const float*)d_in[4];
  const float* b1 = (const float*)d_in[5];
  const float* w2 = (const float*)d_in[6];
  const float* wd = (const float*)d_in[7];
  const float* g  = (const float*)d_in[8];
  const float* b  = (const float*)d_in[9];
  const float* fc = (const float*)d_in[10];

  float* ws   = (float*)d_ws;
  float* xT   = ws + WS_XT;
  float* h    = ws + WS_H;
  float* w1T  = ws + WS_W1T;
  float* bnp  = ws + WS_BNP;
  float* bnss = ws + WS_BNSS;
  float* y    = ws + WS_Y;
  float* z    = ws + WS_Z;
  float* pf   = ws + WS_PF;

  float* out0 = (float*)d_out;         // part_classification (P,N,K)
  float* out1 = out0 + P * N * KCLS;   // weighted_part_vector (P,N,C)
  float* out2 = out1 + P * N * C;      // selected_part_feature (P,N,C)

  k0_transpose<<<dim3(32, 64, 3), 256, 0, stream>>>(tf, ts, tl, xT);
  k0b_w1t<<<32, 256, 0, stream>>>(w1, w1T);
  k1_h<<<dim3(16, 32), 256, 0, stream>>>(xT, w1T, h, bnp);
  k2_bnstat<<<1, 768, 0, stream>>>(bnp, g1, b1, bnss);
  k3_score_y<<<dim3(64, 32), 256, 0, stream>>>(xT, h, bnss, w2, tf, y, z, out2);
  k4_wpv<<<dim3(32, 8), 256, 0, stream>>>(y, z, wd, g, b, out1, pf);
  k5_fc<<<dim3(4, 32), 256, 0, stream>>>(pf, fc, out0);
}